// Round 1
// 262.799 us; speedup vs baseline: 1.0206x; 1.0206x over previous
//
#include <hip/hip_runtime.h>

#define EPS 1e-5f

// Problem dims (fixed by setup_inputs)
constexpr int T  = 512;
constexpr int B  = 64;
constexpr int HU = 1024;
constexpr int S  = 1024;
constexpr int P  = T * B;        // 32768 pairs
constexpr int C  = B * HU;       // 65536 output columns of the weighted sum
constexpr int TSPLIT = 32;       // T-chunks for the weighted sum

// ws layout (in floats)
constexpr size_t OFF_SIW0   = 0;          // [64][10]
constexpr size_t OFF_SCORES = 1024;       // [32768]
constexpr size_t OFF_A      = 34816;      // [512]
constexpr size_t OFF_PART   = 35840;      // [32][65536]

// ---------------------------------------------------------------------------
// K0: siW0[b][j] = si[b,:] . W0[0:1024, j]   (64 x 10)
// ---------------------------------------------------------------------------
__global__ __launch_bounds__(256) void k_siw0(const float* __restrict__ si,
                                              const float* __restrict__ W0,
                                              float* __restrict__ out) {
    const int b   = blockIdx.x;     // 0..63
    const int tid = threadIdx.x;    // 0..255, covers k = 4*tid .. 4*tid+3
    const float4 sv = ((const float4*)(si + (size_t)b * S))[tid];
    const float* wp = W0 + (size_t)(4 * tid) * 10;

    float acc[10];
#pragma unroll
    for (int j = 0; j < 10; ++j) acc[j] = 0.f;
#pragma unroll
    for (int d = 0; d < 4; ++d) {
        const float hx = (&sv.x)[d];
#pragma unroll
        for (int j = 0; j < 10; ++j) acc[j] = fmaf(hx, wp[d * 10 + j], acc[j]);
    }
    // wave reduce (width 64)
#pragma unroll
    for (int j = 0; j < 10; ++j) {
#pragma unroll
        for (int off = 32; off > 0; off >>= 1)
            acc[j] += __shfl_down(acc[j], off, 64);
    }
    __shared__ float red[4][10];
    const int wv = tid >> 6, ln = tid & 63;
    if (ln == 0) {
#pragma unroll
        for (int j = 0; j < 10; ++j) red[wv][j] = acc[j];
    }
    __syncthreads();
    if (tid < 10)
        out[(size_t)b * 10 + tid] =
            red[0][tid] + red[1][tid] + red[2][tid] + red[3][tid];
}

// ---------------------------------------------------------------------------
// K1: per-pair MLP score. Block g = t; lane l = b (owns pair p = 64g + l);
// 8 waves, wave w handles k-slice [128w, 128w+128). W0 index is wave-uniform
// -> scalar loads. 512 blocks x 8 waves = 4096 waves = 4/SIMD occupancy.
// ---------------------------------------------------------------------------
__global__ __launch_bounds__(512) void k_scores(
    const float* __restrict__ h,  const float* __restrict__ W0,
    const float* __restrict__ siW0,
    const float* __restrict__ b0, const float* __restrict__ g0,
    const float* __restrict__ be0,const float* __restrict__ m0,
    const float* __restrict__ v0,
    const float* __restrict__ W1, const float* __restrict__ b1,
    const float* __restrict__ g1, const float* __restrict__ be1,
    const float* __restrict__ m1, const float* __restrict__ v1,
    const float* __restrict__ W2, const float* __restrict__ b2,
    float* __restrict__ scores) {
    const int g   = blockIdx.x;          // t
    const int tid = threadIdx.x;
    const int wv  = tid >> 6;            // 0..7
    const int ln  = tid & 63;            // = b
    const int p   = g * 64 + ln;
    const float* hrow = h + (size_t)p * HU;
    const int k0 = __builtin_amdgcn_readfirstlane(wv * 128);

    float acc[10];
#pragma unroll
    for (int j = 0; j < 10; ++j) acc[j] = 0.f;

#pragma unroll 8
    for (int i = 0; i < 32; ++i) {
        const int k = k0 + 4 * i;                       // wave-uniform
        const float4 hv = *(const float4*)(hrow + k);   // per-lane row stream
        const float* wp = W0 + (size_t)(1024 + k) * 10; // uniform -> scalar loads
#pragma unroll
        for (int d = 0; d < 4; ++d) {
            const float hx = (&hv.x)[d];
#pragma unroll
            for (int j = 0; j < 10; ++j)
                acc[j] = fmaf(hx, wp[d * 10 + j], acc[j]);
        }
    }

    __shared__ float part[8][64][10];
#pragma unroll
    for (int j = 0; j < 10; ++j) part[wv][ln][j] = acc[j];
    __syncthreads();

    if (wv == 0) {
        float y[10];
#pragma unroll
        for (int j = 0; j < 10; ++j) {
            float u = siW0[(size_t)ln * 10 + j] + b0[j];
#pragma unroll
            for (int w = 0; w < 8; ++w) u += part[w][ln][j];
            u = (u - m0[j]) * (1.0f / sqrtf(v0[j] + EPS)) * g0[j] + be0[j];
            y[j] = fmaxf(u, 0.f);
        }
        float z[5];
#pragma unroll
        for (int i = 0; i < 5; ++i) {
            float u = b1[i];
#pragma unroll
            for (int j = 0; j < 10; ++j) u = fmaf(y[j], W1[j * 5 + i], u);
            u = (u - m1[i]) * (1.0f / sqrtf(v1[i] + EPS)) * g1[i] + be1[i];
            z[i] = fmaxf(u, 0.f);
        }
        float sc = b2[0];
#pragma unroll
        for (int i = 0; i < 5; ++i) sc = fmaf(z[i], W2[i], sc);
        scores[p] = sc;
    }
}

// ---------------------------------------------------------------------------
// K2: global softmax over all 32768 scores; write a[0:512] (flat order).
// Single pass: each thread holds its 32 scores in registers (8 x float4),
// so max / sum / output all come from registers instead of 3 memory sweeps.
// ---------------------------------------------------------------------------
__global__ __launch_bounds__(1024) void k_softmax(const float* __restrict__ scores,
                                                  float* __restrict__ a) {
    const int tid = threadIdx.x;   // 1024 threads
    __shared__ float red[16];
    __shared__ float s_m, s_z;

    float4 v[8];
#pragma unroll
    for (int q = 0; q < 8; ++q)
        v[q] = ((const float4*)scores)[tid + 1024 * q];   // coalesced, independent

    float mx = -3.0e38f;
#pragma unroll
    for (int q = 0; q < 8; ++q) {
        mx = fmaxf(mx, fmaxf(fmaxf(v[q].x, v[q].y), fmaxf(v[q].z, v[q].w)));
    }
#pragma unroll
    for (int off = 32; off > 0; off >>= 1)
        mx = fmaxf(mx, __shfl_down(mx, off, 64));
    if ((tid & 63) == 0) red[tid >> 6] = mx;
    __syncthreads();
    if (tid == 0) {
        float m = red[0];
        for (int i = 1; i < 16; ++i) m = fmaxf(m, red[i]);
        s_m = m;
    }
    __syncthreads();
    const float m = s_m;

    float sum = 0.f;
#pragma unroll
    for (int q = 0; q < 8; ++q) {
        sum += expf(v[q].x - m) + expf(v[q].y - m) +
               expf(v[q].z - m) + expf(v[q].w - m);
    }
#pragma unroll
    for (int off = 32; off > 0; off >>= 1)
        sum += __shfl_down(sum, off, 64);
    if ((tid & 63) == 0) red[tid >> 6] = sum;
    __syncthreads();
    if (tid == 0) {
        float z = 0.f;
        for (int i = 0; i < 16; ++i) z += red[i];
        s_z = z;
    }
    __syncthreads();

    // scores[0:512] live in v[0] of threads 0..127 (float4 index tid)
    if (tid < T / 4) {
        const float inv = 1.0f / s_z;
        float4 o;
        o.x = expf(v[0].x - m) * inv;
        o.y = expf(v[0].y - m) * inv;
        o.z = expf(v[0].z - m) * inv;
        o.w = expf(v[0].w - m) * inv;
        ((float4*)a)[tid] = o;
    }
}

// ---------------------------------------------------------------------------
// K3: partial weighted sums. block = (ts, cb); ts in [0,32) covers 16 taus,
// cb in [0,64) covers 1024 columns. 2048 blocks -> ~8 waves/SIMD; 16 fully
// unrolled independent float4 loads per thread.
// ---------------------------------------------------------------------------
__global__ __launch_bounds__(256) void k_wsum(const float* __restrict__ h,
                                              const float* __restrict__ a,
                                              float* __restrict__ part) {
    const int cb = blockIdx.x & 63;
    const int ts = blockIdx.x >> 6;          // 0..31
    const int c  = cb * 1024 + threadIdx.x * 4;
    const float* hp = h + (size_t)ts * 16 * C + c;
    const float* ap = a + ts * 16;

    float4 acc = {0.f, 0.f, 0.f, 0.f};
#pragma unroll
    for (int i = 0; i < 16; ++i) {
        const float av = ap[i];                       // uniform -> s_load
        const float4 hv = *(const float4*)(hp + (size_t)i * C);
        acc.x = fmaf(av, hv.x, acc.x);
        acc.y = fmaf(av, hv.y, acc.y);
        acc.z = fmaf(av, hv.z, acc.z);
        acc.w = fmaf(av, hv.w, acc.w);
    }
    *(float4*)(part + (size_t)ts * C + c) = acc;
}

// ---------------------------------------------------------------------------
// K4: reduce 32 partials -> out (64 x 1024)
// ---------------------------------------------------------------------------
__global__ __launch_bounds__(64) void k_reduce(const float* __restrict__ part,
                                               float* __restrict__ out) {
    const int c = blockIdx.x * 256 + threadIdx.x * 4;
    float4 s = {0.f, 0.f, 0.f, 0.f};
#pragma unroll 8
    for (int ts = 0; ts < TSPLIT; ++ts) {
        const float4 v = *(const float4*)(part + (size_t)ts * C + c);
        s.x += v.x; s.y += v.y; s.z += v.z; s.w += v.w;
    }
    *(float4*)(out + c) = s;
}

// ---------------------------------------------------------------------------
extern "C" void kernel_launch(void* const* d_in, const int* in_sizes, int n_in,
                              void* d_out, int out_size, void* d_ws, size_t ws_size,
                              hipStream_t stream) {
    const float* si  = (const float*)d_in[0];
    const float* h   = (const float*)d_in[1];
    const float* W0  = (const float*)d_in[2];
    const float* b0  = (const float*)d_in[3];
    const float* g0  = (const float*)d_in[4];
    const float* be0 = (const float*)d_in[5];
    const float* m0  = (const float*)d_in[6];
    const float* v0  = (const float*)d_in[7];
    const float* W1  = (const float*)d_in[8];
    const float* b1  = (const float*)d_in[9];
    const float* g1  = (const float*)d_in[10];
    const float* be1 = (const float*)d_in[11];
    const float* m1  = (const float*)d_in[12];
    const float* v1  = (const float*)d_in[13];
    const float* W2  = (const float*)d_in[14];
    const float* b2  = (const float*)d_in[15];

    float* ws     = (float*)d_ws;
    float* siW0   = ws + OFF_SIW0;
    float* scores = ws + OFF_SCORES;
    float* a      = ws + OFF_A;
    float* part   = ws + OFF_PART;
    float* out    = (float*)d_out;

    hipLaunchKernelGGL(k_siw0,    dim3(64),   dim3(256),  0, stream, si, W0, siW0);
    hipLaunchKernelGGL(k_scores,  dim3(512),  dim3(512),  0, stream, h, W0, siW0,
                       b0, g0, be0, m0, v0, W1, b1, g1, be1, m1, v1, W2, b2, scores);
    hipLaunchKernelGGL(k_softmax, dim3(1),    dim3(1024), 0, stream, scores, a);
    hipLaunchKernelGGL(k_wsum,    dim3(2048), dim3(256),  0, stream, h, a, part);
    hipLaunchKernelGGL(k_reduce,  dim3(256),  dim3(64),   0, stream, part, out);
}